// Round 1
// baseline (107.928 us; speedup 1.0000x reference)
//
#include <hip/hip_runtime.h>
#include <math.h>

#define B_  16
#define C_  2048
#define H_  64
#define W_  64
#define P_  16
#define CR_ 128
#define PS_ 16

// Kernel 1: y[b][c] = mean of x[b,c,16:32,16:32]. One wave per (b,c).
__global__ void k_mean(const float* __restrict__ x, float* __restrict__ y) {
    int wave = blockIdx.x * (blockDim.x >> 6) + (threadIdx.x >> 6); // [0, B*C)
    int lane = threadIdx.x & 63;
    const float* base = x + (size_t)wave * (H_ * W_) + PS_ * W_ + PS_;
    int row = lane >> 2;            // 0..15
    int col = (lane & 3) * 4;       // 0,4,8,12
    float4 v = *reinterpret_cast<const float4*>(base + row * W_ + col);
    float s = v.x + v.y + v.z + v.w;
    #pragma unroll
    for (int m = 32; m >= 1; m >>= 1) s += __shfl_xor(s, m, 64);
    if (lane == 0) y[wave] = s * (1.0f / 256.0f);
}

// Kernel 2: h[p][b][k] = relu(sum_c W1[p][k][c] * y[b][c]).
// Thread t: b = t&15 (16 lanes broadcast same W1 row), pk = t>>4.
__global__ void k_fc1(const float* __restrict__ w1, const float* __restrict__ y,
                      float* __restrict__ h) {
    int t  = blockIdx.x * blockDim.x + threadIdx.x;  // [0, P*CR*B)
    int b  = t & 15;
    int pk = t >> 4;                                  // p*128 + k
    const float4* wr = reinterpret_cast<const float4*>(w1) + (size_t)pk * (C_ / 4);
    const float4* yb = reinterpret_cast<const float4*>(y) + (size_t)b * (C_ / 4);
    float acc = 0.0f;
    for (int i = 0; i < C_ / 4; ++i) {
        float4 a = wr[i];
        float4 v = yb[i];
        acc += a.x * v.x + a.y * v.y + a.z * v.z + a.w * v.w;
    }
    int p = pk >> 7, k = pk & 127;
    h[(p * B_ + b) * CR_ + k] = fmaxf(acc, 0.0f);
}

// Kernel 3: out[p][b][c] = sigmoid(sum_k W2[p][c][k] * h[p][b][k]).
// Thread t = (p*16+b)*2048 + c  → coalesced output writes.
__global__ void k_fc2(const float* __restrict__ w2, const float* __restrict__ h,
                      float* __restrict__ out) {
    int t  = blockIdx.x * blockDim.x + threadIdx.x;  // [0, P*B*C)
    int c  = t & (C_ - 1);
    int pb = t >> 11;                                 // p*16 + b
    int p  = pb >> 4;
    const float4* wr = reinterpret_cast<const float4*>(w2) + ((size_t)(p * C_ + c)) * (CR_ / 4);
    const float4* hv = reinterpret_cast<const float4*>(h) + (size_t)pb * (CR_ / 4);
    float acc = 0.0f;
    #pragma unroll
    for (int i = 0; i < CR_ / 4; ++i) {
        float4 a = wr[i];
        float4 v = hv[i];
        acc += a.x * v.x + a.y * v.y + a.z * v.z + a.w * v.w;
    }
    out[t] = 1.0f / (1.0f + expf(-acc));
}

extern "C" void kernel_launch(void* const* d_in, const int* in_sizes, int n_in,
                              void* d_out, int out_size, void* d_ws, size_t ws_size,
                              hipStream_t stream) {
    const float* x  = (const float*)d_in[0];
    const float* w1 = (const float*)d_in[1];
    const float* w2 = (const float*)d_in[2];
    float* out = (float*)d_out;
    float* y = (float*)d_ws;                 // B*C   = 32768 floats
    float* h = y + B_ * C_;                  // P*B*CR = 32768 floats

    // 1) patch mean: B*C waves, 4 waves/block
    k_mean<<<(B_ * C_) / 4, 256, 0, stream>>>(x, y);
    // 2) FC1 + relu: 32768 threads, 1 wave/block for spread
    k_fc1<<<(P_ * CR_ * B_) / 64, 64, 0, stream>>>(w1, y, h);
    // 3) FC2 + sigmoid: 524288 threads
    k_fc2<<<(P_ * B_ * C_) / 256, 256, 0, stream>>>(w2, h, out);
}

// Round 2
// 79.208 us; speedup vs baseline: 1.3626x; 1.3626x over previous
//
#include <hip/hip_runtime.h>
#include <math.h>

#define B_  16
#define C_  2048
#define H_  64
#define W_  64
#define P_  16
#define CR_ 128
#define PS_ 16

// Kernel 1: y[b][c] = mean of x[b,c,16:32,16:32]. One wave per (b,c).
// Each patch row is exactly one 64B line (base offset 4160B = 65*64B, row stride 256B).
__global__ void k_mean(const float* __restrict__ x, float* __restrict__ y) {
    int wave = blockIdx.x * (blockDim.x >> 6) + (threadIdx.x >> 6); // [0, B*C)
    int lane = threadIdx.x & 63;
    const float* base = x + (size_t)wave * (H_ * W_) + PS_ * W_ + PS_;
    int row = lane >> 2;            // 0..15
    int col = (lane & 3) * 4;       // 0,4,8,12
    float4 v = *reinterpret_cast<const float4*>(base + row * W_ + col);
    float s = v.x + v.y + v.z + v.w;
    #pragma unroll
    for (int m = 32; m >= 1; m >>= 1) s += __shfl_xor(s, m, 64);
    if (lane == 0) y[wave] = s * (1.0f / 256.0f);
}

// Kernel 2: h[p][b][k] = relu(sum_c W1[p][k][c] * y[b][c]).
// One wave per (p,k): lanes split C (coalesced 1KB wave-loads of the W1 row),
// acc[16] per lane (one per b), 64-lane butterfly reduce at the end.
__global__ void k_fc1(const float* __restrict__ w1, const float* __restrict__ y,
                      float* __restrict__ h) {
    int wid  = blockIdx.x * (blockDim.x >> 6) + (threadIdx.x >> 6); // [0, P*CR)
    int lane = threadIdx.x & 63;
    int p = wid >> 7, k = wid & 127;

    const float4* wr = reinterpret_cast<const float4*>(w1) + (size_t)wid * (C_ / 4);
    const float4* yv = reinterpret_cast<const float4*>(y);

    float acc[B_];
    #pragma unroll
    for (int b = 0; b < B_; ++b) acc[b] = 0.0f;

    #pragma unroll
    for (int i = 0; i < C_ / 256; ++i) {          // 8 iterations
        int c4 = i * 64 + lane;                   // float4 index within row
        float4 w4 = wr[c4];
        #pragma unroll
        for (int b = 0; b < B_; ++b) {
            float4 v = yv[b * (C_ / 4) + c4];
            acc[b] += w4.x * v.x;
            acc[b] += w4.y * v.y;
            acc[b] += w4.z * v.z;
            acc[b] += w4.w * v.w;
        }
    }

    // Butterfly reduce each acc[b] across the 64 lanes.
    #pragma unroll
    for (int b = 0; b < B_; ++b) {
        #pragma unroll
        for (int m = 32; m >= 1; m >>= 1) acc[b] += __shfl_xor(acc[b], m, 64);
    }

    // Static-index select: lane b takes acc[b] (no runtime-indexed reg array).
    float v = acc[0];
    #pragma unroll
    for (int b = 1; b < B_; ++b) v = (lane == b) ? acc[b] : v;

    if (lane < B_) h[(p * B_ + lane) * CR_ + k] = fmaxf(v, 0.0f);
}

// Kernel 3: out[p][b][c] = sigmoid(sum_k W2[p][c][k] * h[p][b][k]).
// Thread t = (p*16+b)*2048 + c  → coalesced output writes; W2 rows stream via L1,
// 16 b-blocks sharing a W2 tile are stride-8 blocks apart → same XCD L2.
__global__ void k_fc2(const float* __restrict__ w2, const float* __restrict__ h,
                      float* __restrict__ out) {
    int t  = blockIdx.x * blockDim.x + threadIdx.x;  // [0, P*B*C)
    int c  = t & (C_ - 1);
    int pb = t >> 11;                                 // p*16 + b
    int p  = pb >> 4;
    const float4* wr = reinterpret_cast<const float4*>(w2) + ((size_t)(p * C_ + c)) * (CR_ / 4);
    const float4* hv = reinterpret_cast<const float4*>(h) + (size_t)pb * (CR_ / 4);
    float acc = 0.0f;
    #pragma unroll
    for (int i = 0; i < CR_ / 4; ++i) {
        float4 a = wr[i];
        float4 v = hv[i];
        acc += a.x * v.x + a.y * v.y + a.z * v.z + a.w * v.w;
    }
    out[t] = 1.0f / (1.0f + expf(-acc));
}

extern "C" void kernel_launch(void* const* d_in, const int* in_sizes, int n_in,
                              void* d_out, int out_size, void* d_ws, size_t ws_size,
                              hipStream_t stream) {
    const float* x  = (const float*)d_in[0];
    const float* w1 = (const float*)d_in[1];
    const float* w2 = (const float*)d_in[2];
    float* out = (float*)d_out;
    float* y = (float*)d_ws;                 // B*C    = 32768 floats
    float* h = y + B_ * C_;                  // P*B*CR = 32768 floats

    // 1) patch mean: B*C waves, 4 waves/block
    k_mean<<<(B_ * C_) / 4, 256, 0, stream>>>(x, y);
    // 2) FC1 + relu: one wave per (p,k) = 2048 waves, 4 waves/block
    k_fc1<<<(P_ * CR_) / 4, 256, 0, stream>>>(w1, y, h);
    // 3) FC2 + sigmoid: 524288 threads
    k_fc2<<<(P_ * B_ * C_) / 256, 256, 0, stream>>>(w2, h, out);
}

// Round 3
// 48.018 us; speedup vs baseline: 2.2476x; 1.6495x over previous
//
#include <hip/hip_runtime.h>
#include <math.h>

#define B_  16
#define C_  2048
#define H_  64
#define W_  64
#define P_  16
#define CR_ 128
#define PS_ 16

// Kernel 1: y[b][c] = mean of x[b,c,16:32,16:32]. One wave per (b,c).
// Each patch row is exactly one 64B chunk (base offset 4160B, row stride 256B).
__global__ void k_mean(const float* __restrict__ x, float* __restrict__ y) {
    int wave = blockIdx.x * (blockDim.x >> 6) + (threadIdx.x >> 6); // [0, B*C)
    int lane = threadIdx.x & 63;
    const float* base = x + (size_t)wave * (H_ * W_) + PS_ * W_ + PS_;
    int row = lane >> 2;            // 0..15
    int col = (lane & 3) * 4;       // 0,4,8,12
    float4 v = *reinterpret_cast<const float4*>(base + row * W_ + col);
    float s = v.x + v.y + v.z + v.w;
    #pragma unroll
    for (int m = 32; m >= 1; m >>= 1) s += __shfl_xor(s, m, 64);
    if (lane == 0) y[wave] = s * (1.0f / 256.0f);
}

// Kernel 2: h[p][b][k] = relu(sum_c W1[p][k][c] * y[b][c]).
// One wave per (p,k): lanes split C (coalesced 1KB wave-loads of the W1 row),
// acc[16] per lane (one per b); y reads stay L1-resident (16KB active window).
__global__ void k_fc1(const float* __restrict__ w1, const float* __restrict__ y,
                      float* __restrict__ h) {
    int wid  = blockIdx.x * (blockDim.x >> 6) + (threadIdx.x >> 6); // [0, P*CR)
    int lane = threadIdx.x & 63;
    int p = wid >> 7, k = wid & 127;

    const float4* wr = reinterpret_cast<const float4*>(w1) + (size_t)wid * (C_ / 4);
    const float4* yv = reinterpret_cast<const float4*>(y);

    float acc[B_];
    #pragma unroll
    for (int b = 0; b < B_; ++b) acc[b] = 0.0f;

    #pragma unroll
    for (int i = 0; i < C_ / 256; ++i) {          // 8 iterations
        int c4 = i * 64 + lane;                   // float4 index within row
        float4 w4 = wr[c4];
        #pragma unroll
        for (int b = 0; b < B_; ++b) {
            float4 v = yv[b * (C_ / 4) + c4];
            acc[b] += w4.x * v.x;
            acc[b] += w4.y * v.y;
            acc[b] += w4.z * v.z;
            acc[b] += w4.w * v.w;
        }
    }

    #pragma unroll
    for (int b = 0; b < B_; ++b) {
        #pragma unroll
        for (int m = 32; m >= 1; m >>= 1) acc[b] += __shfl_xor(acc[b], m, 64);
    }

    float v = acc[0];
    #pragma unroll
    for (int b = 1; b < B_; ++b) v = (lane == b) ? acc[b] : v;

    if (lane < B_) h[(p * B_ + lane) * CR_ + k] = fmaxf(v, 0.0f);
}

// Kernel 3 (wave-cooperative): out[p][b][c] = sigmoid(sum_k W2[p][c][k] * h[p][b][k]).
// Wave = (p, 16 consecutive c rows). lane: row = lane>>2, q = lane&3.
// Lane covers k4-chunks {q+4j, j=0..7}: each global load instr = 16 rows x 64B
// fully-used segments (coalesced within quad). h[p] staged in LDS (8KB);
// compute h-reads are 4-distinct-addr + 16-way broadcast -> conflict-free.
__global__ void __launch_bounds__(256) k_fc2(const float* __restrict__ w2,
                                             const float* __restrict__ h,
                                             float* __restrict__ out) {
    __shared__ float hs[B_ * CR_];                // 8 KiB

    int wib  = threadIdx.x >> 6;                  // wave in block 0..3
    int wid  = blockIdx.x * 4 + wib;              // [0, P*C/16) = 2048
    int lane = threadIdx.x & 63;
    int p  = wid >> 7;                            // 128 waves per p (block-aligned)
    int c0 = (wid & 127) << 4;
    int row = lane >> 2;                          // 0..15
    int q   = lane & 3;

    // Stage h[p][0:16][0:128] (all 4 waves share p).
    const float4* hsrc = reinterpret_cast<const float4*>(h + (size_t)p * B_ * CR_);
    float4* hdst = reinterpret_cast<float4*>(hs);
    #pragma unroll
    for (int i = 0; i < 2; ++i)
        hdst[threadIdx.x + i * 256] = hsrc[threadIdx.x + i * 256];
    __syncthreads();

    // W2 row for this lane: float4 base index of row (c0+row).
    const float4* wr = reinterpret_cast<const float4*>(w2)
                     + ((size_t)p * C_ + c0 + row) * (CR_ / 4);
    const float4* hv = reinterpret_cast<const float4*>(hs);

    float acc[B_];
    #pragma unroll
    for (int b = 0; b < B_; ++b) acc[b] = 0.0f;

    #pragma unroll
    for (int j = 0; j < 8; ++j) {
        float4 w4 = wr[q + 4 * j];                // coalesced across quad
        #pragma unroll
        for (int b = 0; b < B_; ++b) {
            float4 h4 = hv[b * (CR_ / 4) + q + 4 * j];
            acc[b] += w4.x * h4.x;
            acc[b] += w4.y * h4.y;
            acc[b] += w4.z * h4.z;
            acc[b] += w4.w * h4.w;
        }
    }

    // Sum the 4 q-lanes of each row.
    #pragma unroll
    for (int b = 0; b < B_; ++b) {
        acc[b] += __shfl_xor(acc[b], 1, 64);
        acc[b] += __shfl_xor(acc[b], 2, 64);
    }

    // Lane q writes b in {4q..4q+3}; static-index select of acc.
    #pragma unroll
    for (int i = 0; i < 4; ++i) {
        float v = acc[i];                          // q==0
        v = (q == 1) ? acc[4 + i]  : v;
        v = (q == 2) ? acc[8 + i]  : v;
        v = (q == 3) ? acc[12 + i] : v;
        int b = q * 4 + i;
        out[(((size_t)p * B_ + b) << 11) + c0 + row] = 1.0f / (1.0f + expf(-v));
    }
}

extern "C" void kernel_launch(void* const* d_in, const int* in_sizes, int n_in,
                              void* d_out, int out_size, void* d_ws, size_t ws_size,
                              hipStream_t stream) {
    const float* x  = (const float*)d_in[0];
    const float* w1 = (const float*)d_in[1];
    const float* w2 = (const float*)d_in[2];
    float* out = (float*)d_out;
    float* y = (float*)d_ws;                 // B*C    = 32768 floats
    float* h = y + B_ * C_;                  // P*B*CR = 32768 floats

    // 1) patch mean: B*C waves, 4 waves/block
    k_mean<<<(B_ * C_) / 4, 256, 0, stream>>>(x, y);
    // 2) FC1 + relu: one wave per (p,k) = 2048 waves, 4 waves/block
    k_fc1<<<(P_ * CR_) / 4, 256, 0, stream>>>(w1, y, h);
    // 3) FC2 + sigmoid: one wave per 16 c-rows = 2048 waves, 4 waves/block
    k_fc2<<<(P_ * C_ / 16) / 4, 256, 0, stream>>>(w2, h, out);
}

// Round 4
// 39.002 us; speedup vs baseline: 2.7672x; 1.2312x over previous
//
#include <hip/hip_runtime.h>
#include <math.h>

#define B_  16
#define C_  2048
#define H_  64
#define W_  64
#define P_  16
#define CR_ 128
#define PS_ 16

// Kernel 1: y[b][c] = mean of x[b,c,16:32,16:32]. One wave per 4 consecutive
// (b,c) patches: 4 independent 64B-aligned loads in flight per wave.
__global__ void k_mean(const float* __restrict__ x, float* __restrict__ y) {
    int wave = blockIdx.x * (blockDim.x >> 6) + (threadIdx.x >> 6); // [0, B*C/4)
    int lane = threadIdx.x & 63;
    int row = lane >> 2;            // 0..15
    int col = (lane & 3) * 4;       // 0,4,8,12
    const float* base = x + (size_t)wave * 4 * (H_ * W_) + PS_ * W_ + PS_
                      + row * W_ + col;
    float4 v0 = *reinterpret_cast<const float4*>(base);
    float4 v1 = *reinterpret_cast<const float4*>(base + H_ * W_);
    float4 v2 = *reinterpret_cast<const float4*>(base + 2 * H_ * W_);
    float4 v3 = *reinterpret_cast<const float4*>(base + 3 * H_ * W_);
    float s0 = v0.x + v0.y + v0.z + v0.w;
    float s1 = v1.x + v1.y + v1.z + v1.w;
    float s2 = v2.x + v2.y + v2.z + v2.w;
    float s3 = v3.x + v3.y + v3.z + v3.w;
    #pragma unroll
    for (int m = 32; m >= 1; m >>= 1) {
        s0 += __shfl_xor(s0, m, 64);
        s1 += __shfl_xor(s1, m, 64);
        s2 += __shfl_xor(s2, m, 64);
        s3 += __shfl_xor(s3, m, 64);
    }
    float v = s0;                    // static select, no runtime-indexed array
    v = (lane == 1) ? s1 : v;
    v = (lane == 2) ? s2 : v;
    v = (lane == 3) ? s3 : v;
    if (lane < 4) y[wave * 4 + lane] = v * (1.0f / 256.0f);
}

// Kernel 2: h[p][b][k] = relu(sum_c W1[p][k][c] * y[b][c]).
// Grid = 256 blocks (1/CU). Block stages ALL of y (128 KiB) into LDS once,
// then handles 8 (p,k) rows: 2 rows per wave, W1 register-prefetched across
// the 8 c-chunks so HBM latency hides under the FMA+LDS phase.
__global__ void __launch_bounds__(256) k_fc1(const float* __restrict__ w1,
                                             const float* __restrict__ y,
                                             float* __restrict__ h) {
    __shared__ float ys[B_ * C_];                 // 128 KiB
    int tid  = threadIdx.x;
    int wib  = tid >> 6;
    int lane = tid & 63;

    const float4* ysrc = reinterpret_cast<const float4*>(y);
    float4* ydst = reinterpret_cast<float4*>(ys);
    #pragma unroll 8
    for (int i = 0; i < 32; ++i)
        ydst[tid + 256 * i] = ysrc[tid + 256 * i];
    __syncthreads();

    int r0 = blockIdx.x * 8 + wib * 2;            // even row id; r0+1 same p
    const float4* wr0 = reinterpret_cast<const float4*>(w1) + (size_t)r0 * (C_ / 4);
    const float4* wr1 = wr0 + (C_ / 4);

    float acc0[B_], acc1[B_];
    #pragma unroll
    for (int b = 0; b < B_; ++b) { acc0[b] = 0.0f; acc1[b] = 0.0f; }

    float4 pa = wr0[lane];
    float4 pb = wr1[lane];
    #pragma unroll
    for (int i = 0; i < 8; ++i) {
        float4 wa = pa, wb = pb;
        if (i < 7) { pa = wr0[(i + 1) * 64 + lane]; pb = wr1[(i + 1) * 64 + lane]; }
        const float4* yrow = reinterpret_cast<const float4*>(ys) + i * 64 + lane;
        #pragma unroll
        for (int b = 0; b < B_; ++b) {
            float4 v = yrow[b * (C_ / 4)];
            acc0[b] += wa.x * v.x + wa.y * v.y + wa.z * v.z + wa.w * v.w;
            acc1[b] += wb.x * v.x + wb.y * v.y + wb.z * v.z + wb.w * v.w;
        }
    }

    #pragma unroll
    for (int b = 0; b < B_; ++b) {
        #pragma unroll
        for (int m = 32; m >= 1; m >>= 1) {
            acc0[b] += __shfl_xor(acc0[b], m, 64);
            acc1[b] += __shfl_xor(acc1[b], m, 64);
        }
    }

    float v0 = acc0[0], v1 = acc1[0];
    #pragma unroll
    for (int b = 1; b < B_; ++b) {
        v0 = (lane == b) ? acc0[b] : v0;
        v1 = (lane == b) ? acc1[b] : v1;
    }
    if (lane < B_) {
        int p = r0 >> 7, k = r0 & 127;
        h[(p * B_ + lane) * CR_ + k]     = fmaxf(v0, 0.0f);
        h[(p * B_ + lane) * CR_ + k + 1] = fmaxf(v1, 0.0f);
    }
}

// Kernel 3 (wave-cooperative): out[p][b][c] = sigmoid(sum_k W2[p][c][k] * h[p][b][k]).
// Wave = (p, 16 consecutive c rows); W2 read coalesced exactly once; h[p] in LDS.
__global__ void __launch_bounds__(256) k_fc2(const float* __restrict__ w2,
                                             const float* __restrict__ h,
                                             float* __restrict__ out) {
    __shared__ float hs[B_ * CR_];                // 8 KiB

    int wib  = threadIdx.x >> 6;
    int wid  = blockIdx.x * 4 + wib;              // [0, 2048)
    int lane = threadIdx.x & 63;
    int p  = wid >> 7;
    int c0 = (wid & 127) << 4;
    int row = lane >> 2;
    int q   = lane & 3;

    const float4* hsrc = reinterpret_cast<const float4*>(h + (size_t)p * B_ * CR_);
    float4* hdst = reinterpret_cast<float4*>(hs);
    #pragma unroll
    for (int i = 0; i < 2; ++i)
        hdst[threadIdx.x + i * 256] = hsrc[threadIdx.x + i * 256];
    __syncthreads();

    const float4* wr = reinterpret_cast<const float4*>(w2)
                     + ((size_t)p * C_ + c0 + row) * (CR_ / 4);
    const float4* hv = reinterpret_cast<const float4*>(hs);

    float acc[B_];
    #pragma unroll
    for (int b = 0; b < B_; ++b) acc[b] = 0.0f;

    #pragma unroll
    for (int j = 0; j < 8; ++j) {
        float4 w4 = wr[q + 4 * j];
        #pragma unroll
        for (int b = 0; b < B_; ++b) {
            float4 h4 = hv[b * (CR_ / 4) + q + 4 * j];
            acc[b] += w4.x * h4.x + w4.y * h4.y + w4.z * h4.z + w4.w * h4.w;
        }
    }

    #pragma unroll
    for (int b = 0; b < B_; ++b) {
        acc[b] += __shfl_xor(acc[b], 1, 64);
        acc[b] += __shfl_xor(acc[b], 2, 64);
    }

    #pragma unroll
    for (int i = 0; i < 4; ++i) {
        float v = acc[i];
        v = (q == 1) ? acc[4 + i]  : v;
        v = (q == 2) ? acc[8 + i]  : v;
        v = (q == 3) ? acc[12 + i] : v;
        int b = q * 4 + i;
        out[(((size_t)p * B_ + b) << 11) + c0 + row] = 1.0f / (1.0f + expf(-v));
    }
}

extern "C" void kernel_launch(void* const* d_in, const int* in_sizes, int n_in,
                              void* d_out, int out_size, void* d_ws, size_t ws_size,
                              hipStream_t stream) {
    const float* x  = (const float*)d_in[0];
    const float* w1 = (const float*)d_in[1];
    const float* w2 = (const float*)d_in[2];
    float* out = (float*)d_out;
    float* y = (float*)d_ws;                 // B*C    = 32768 floats
    float* h = y + B_ * C_;                  // P*B*CR = 32768 floats

    // 1) patch mean: 8192 waves, 4 patches each
    k_mean<<<(B_ * C_ / 4) / 4, 256, 0, stream>>>(x, y);
    // 2) FC1 + relu: 256 blocks, y staged in LDS, 8 rows/block
    k_fc1<<<256, 256, 0, stream>>>(w1, y, h);
    // 3) FC2 + sigmoid: one wave per 16 c-rows = 2048 waves
    k_fc2<<<(P_ * C_ / 16) / 4, 256, 0, stream>>>(w2, h, out);
}